// Round 10
// baseline (148.571 us; speedup 1.0000x reference)
//
#include <hip/hip_runtime.h>
#include <stdint.h>

#define B_  2
#define L_  2048
#define HD_ 1024
#define H_  16
#define D_  64

typedef unsigned short u16;
typedef __attribute__((ext_vector_type(8))) short bf16x8;
typedef __attribute__((ext_vector_type(4))) float f32x4;

#define MFMA16(a, b, c) __builtin_amdgcn_mfma_f32_16x16x32_bf16((a), (b), (c), 0, 0, 0)

__device__ __forceinline__ void gload16(const void* g, void* l) {
  __builtin_amdgcn_global_load_lds((const __attribute__((address_space(1))) void*)g,
                                   (__attribute__((address_space(3))) void*)l, 16, 0, 0);
}

__device__ __forceinline__ u16 f2bf(float f) {
  union { float f; uint32_t u; } c; c.f = f;
  uint32_t u = c.u + 0x7FFFu + ((c.u >> 16) & 1u);
  return (u16)(u >> 16);
}

__device__ __forceinline__ float bf2f(u16 v) {
  union { uint32_t u; float f; } c; c.u = (uint32_t)v << 16;
  return c.f;
}

__device__ __forceinline__ uint32_t cvt_pk_bf16(float lo, float hi) {
  uint32_t r;
  asm("v_cvt_pk_bf16_f32 %0, %1, %2" : "=v"(r) : "v"(lo), "v"(hi));
  return r;
}

// ---------------- fused cast f32 -> bf16 for x and y (8 elems/thread) ----------------
__global__ void cast2_k(const float* __restrict__ x, const float* __restrict__ y,
                        u16* __restrict__ xb, u16* __restrict__ yb) {
  int bid = blockIdx.x;
  const float* in = bid < 2048 ? x : y;
  u16* out = bid < 2048 ? xb : yb;
  int i = ((bid & 2047) * 256 + threadIdx.x) * 8;   // 2048*256*8 == 4M exact
  float4 a = *(const float4*)(in + i);
  float4 b = *(const float4*)(in + i + 4);
  bf16x8 r;
  r[0] = (short)f2bf(a.x); r[1] = (short)f2bf(a.y); r[2] = (short)f2bf(a.z); r[3] = (short)f2bf(a.w);
  r[4] = (short)f2bf(b.x); r[5] = (short)f2bf(b.y); r[6] = (short)f2bf(b.z); r[7] = (short)f2bf(b.w);
  *(bf16x8*)(out + i) = r;
}

// ---------------- fused transpose+cast of all three weights: dst[n][k]=bf16(src[k][n]) ----
__global__ void wtrans_k(const float* __restrict__ Wq, const float* __restrict__ Wkv,
                         const float* __restrict__ Wp,
                         u16* __restrict__ Wqt, u16* __restrict__ Wkvt, u16* __restrict__ Wpt) {
  int z = blockIdx.z;
  const float* src = z == 0 ? Wq : (z == 1 ? Wkv : Wp);
  u16* dst = z == 0 ? Wqt : (z == 1 ? Wkvt : Wpt);
  int Nfull = (z == 1) ? 2048 : 1024;
  int nb = blockIdx.x * 32;
  if (nb >= Nfull) return;               // block-uniform early out (before any barrier)
  __shared__ float tile[32][33];
  int t = threadIdx.x;
  int tc = t & 31, tr = t >> 5;
  int kb = blockIdx.y * 32;
#pragma unroll
  for (int i = 0; i < 4; i++)
    tile[tr + i * 8][tc] = src[(size_t)(kb + tr + i * 8) * Nfull + nb + tc];
  __syncthreads();
#pragma unroll
  for (int i = 0; i < 4; i++) {
    int nl = tr + i * 8;
    dst[(size_t)(nb + nl) * 1024 + kb + tc] = f2bf(tile[tc][nl]);
  }
}

// ---------------- shared GEMM body (unchanged from R7/R8) ----------------
__device__ __forceinline__ void gemm_body(
    char* sA, char* sB,                 // each 2*16384 bytes (double-buffered)
    const u16* __restrict__ A, const u16* __restrict__ Bt,
    const float* __restrict__ bias, void* __restrict__ outp,
    int N, int epi, int bm, int bn)
{
  int t = threadIdx.x;
  int lane = t & 63, w = t >> 6;
  int g = lane >> 4, l15 = lane & 15;
  int wr = w >> 1, wc = w & 1;

  f32x4 zero = {0.f, 0.f, 0.f, 0.f};
  f32x4 acc[4][4];
#pragma unroll
  for (int mi = 0; mi < 4; mi++)
#pragma unroll
    for (int ni = 0; ni < 4; ni++) acc[mi][ni] = zero;

#define GSTAGE(bufi, k0s) do {                                                          \
    _Pragma("unroll")                                                                   \
    for (int it = 0; it < 4; it++) {                                                    \
      int c = it * 256 + t;             /* 0..1023 16B-chunks per matrix */             \
      int r = c >> 3, sp = c & 7;                                                       \
      int off = (sp ^ (r & 7)) << 4;    /* pre-swizzled global source (T2) */           \
      gload16((const char*)(A + (size_t)(bm + r) * 1024 + (k0s)) + off,                 \
              sA + (bufi) * 16384 + c * 16);                                            \
      gload16((const char*)(Bt + (size_t)(bn + r) * 1024 + (k0s)) + off,                \
              sB + (bufi) * 16384 + c * 16);                                            \
    } } while (0)

  GSTAGE(0, 0);
  int buf = 0;
#pragma unroll 1
  for (int kt = 0; kt < 16; kt++) {
    __builtin_amdgcn_sched_barrier(0);
    __builtin_amdgcn_s_barrier();                      // B1: buf^1 free to overwrite
    if (kt < 15) {
      GSTAGE(buf ^ 1, (kt + 1) << 6);                  // next tile's 8 loads in flight
      asm volatile("s_waitcnt vmcnt(8)" ::: "memory"); // own tile's batch landed
    } else {
      asm volatile("s_waitcnt vmcnt(0)" ::: "memory"); // last tile: full drain
    }
    __builtin_amdgcn_s_barrier();                      // B2: tile kt resident block-wide
    __builtin_amdgcn_sched_barrier(0);

    const char* cA = sA + buf * 16384;
    const char* cB = sB + buf * 16384;
#pragma unroll
    for (int kc = 0; kc < 2; kc++) {
      bf16x8 af[4], bfr[4];
#pragma unroll
      for (int mi = 0; mi < 4; mi++) {
        int r = wr * 64 + mi * 16 + l15;
        af[mi] = *(const bf16x8*)(cA + r * 128 + (((kc * 4 + g) ^ (r & 7)) << 4));
      }
#pragma unroll
      for (int ni = 0; ni < 4; ni++) {
        int r = wc * 64 + ni * 16 + l15;
        bfr[ni] = *(const bf16x8*)(cB + r * 128 + (((kc * 4 + g) ^ (r & 7)) << 4));
      }
#pragma unroll
      for (int mi = 0; mi < 4; mi++)
#pragma unroll
        for (int ni = 0; ni < 4; ni++)
          acc[mi][ni] = MFMA16(af[mi], bfr[ni], acc[mi][ni]);
    }
    buf ^= 1;
  }
#undef GSTAGE

  float bv[4];
#pragma unroll
  for (int ni = 0; ni < 4; ni++) bv[ni] = bias[bn + wc * 64 + ni * 16 + l15];

  if (epi == 2) {
    float* fo = (float*)outp;
#pragma unroll
    for (int mi = 0; mi < 4; mi++)
#pragma unroll
      for (int ni = 0; ni < 4; ni++) {
        int n = bn + wc * 64 + ni * 16 + l15;
#pragma unroll
        for (int r = 0; r < 4; r++) {
          int m = bm + wr * 64 + mi * 16 + g * 4 + r;
          fo[(size_t)m * N + n] = acc[mi][ni][r] + bv[ni];
        }
      }
  } else {
    u16* ob = (u16*)outp;
#pragma unroll
    for (int mi = 0; mi < 4; mi++)
#pragma unroll
      for (int ni = 0; ni < 4; ni++) {
        int n = bn + wc * 64 + ni * 16 + l15;
        int kv = n >> 10;          // 0 for epi0 (N=1024)
        int hh = (n >> 6) & 15;
        int dd = n & 63;
        int m0 = bm + wr * 64 + mi * 16 + g * 4;
        int bb = m0 >> 11, lq0 = m0 & 2047;
        if (epi == 1 && kv == 1) {
          // V stored TRANSPOSED: [b,h,d,l]; r -> lq consecutive -> one 8B store
          ushort4 pk;
          pk.x = f2bf(acc[mi][ni][0] + bv[ni]);
          pk.y = f2bf(acc[mi][ni][1] + bv[ni]);
          pk.z = f2bf(acc[mi][ni][2] + bv[ni]);
          pk.w = f2bf(acc[mi][ni][3] + bv[ni]);
          size_t idx = (size_t)(B_ * H_ * L_ * D_) +
                       (((size_t)(bb * H_ + hh) * D_ + dd) * L_ + lq0);
          *(ushort4*)(ob + idx) = pk;
        } else {
#pragma unroll
          for (int r = 0; r < 4; r++) {
            size_t idx = (((size_t)(bb * H_ + hh) * L_ + lq0 + r) * D_) + dd;
            ob[idx] = f2bf(acc[mi][ni][r] + bv[ni]);
          }
        }
      }
  }
}

// fused Q + KV projection: grid (8+16, 32); bx<8 -> Q-GEMM, else KV-GEMM.
__global__ __launch_bounds__(256) void qkv_k(
    const u16* __restrict__ xb, const u16* __restrict__ yb,
    const u16* __restrict__ Wqt, const u16* __restrict__ Wkvt,
    const float* __restrict__ Wq_b, const float* __restrict__ Wkv_b,
    u16* __restrict__ Qout, u16* __restrict__ KVout)
{
  __shared__ char sA[2 * 16384];
  __shared__ char sB[2 * 16384];
  int bx = blockIdx.x, bm = blockIdx.y * 128;
  if (bx < 8)
    gemm_body(sA, sB, xb, Wqt, Wq_b, (void*)Qout, 1024, 0, bm, bx * 128);
  else
    gemm_body(sA, sB, yb, Wkvt, Wkv_b, (void*)KVout, 2048, 1, bm, (bx - 8) * 128);
}

// proj GEMM (epi2, f32 out)
__global__ __launch_bounds__(256) void gemm_k(
    const u16* __restrict__ A, const u16* __restrict__ Bt,
    const float* __restrict__ bias, void* __restrict__ outp, int N)
{
  __shared__ char sA[2 * 16384];
  __shared__ char sB[2 * 16384];
  gemm_body(sA, sB, A, Bt, bias, outp, N, 2, blockIdx.y * 128, blockIdx.x * 128);
}

// ---------------- flash attention v9: split-KV for heavy chunks ----------------
// grid (24,16,2) x 512 threads = 768 blocks, 3/CU (144KB LDS), all resident.
// x 0..15: chunk qb = 15-(x>>1) (>=8) SPLIT in two key halves, part = x&1:
//   part 0 tiles [0,qb+1) (all below diagonal, maskless), part 1 [qb+1, 2qb+2).
//   Writes normalized partial O^ (bf16) + (m,l) f32 -> merged by merge_k.
// x 16..23: chunk qb = 23-x (<8), unsplit, writes Ob directly.
// Block loads now 2..16 tiles (was 2..32) -> balanced drain. Body = proven R8.
__global__ __launch_bounds__(512, 2) void attn_k(
    const u16* __restrict__ Qb, const u16* __restrict__ Kb, const u16* __restrict__ Vt,
    const unsigned char* __restrict__ pad, u16* __restrict__ Ob,
    u16* __restrict__ Opart, float* __restrict__ mlbuf)
{
  __shared__ char sK[2][8192];   // [buf][key 0..63][128B row], slot s at phys s^(key&7)
  __shared__ char sV[2][8192];   // [buf][d 0..63][128B row = 64 keys], slot s^(d&7)
  __shared__ char sP[8][2048];   // per-wave P^T: [q15][128B = 64 keys], slot s^(q15&7)
  int t = threadIdx.x, lane = t & 63, w = t >> 6, g = lane >> 4, l15 = lane & 15;
  int x = blockIdx.x, h = blockIdx.y, b = blockIdx.z, bh = b * H_ + h;

  int qb, kt_lo, kt_hi, part;
  bool split = (x < 16);
  if (split) {
    qb = 15 - (x >> 1);            // 15,15,14,14,...,8,8  (heavy first)
    part = x & 1;
    int half = qb + 1;
    kt_lo = part ? half : 0;
    kt_hi = part ? 2 * qb + 2 : half;
  } else {
    qb = 23 - x;                   // 7,6,...,0
    part = 0;
    kt_lo = 0;
    kt_hi = 2 * qb + 2;
  }

  const u16* Kbh = Kb + (size_t)bh * L_ * D_;
  const u16* Vbh = Vt + (size_t)bh * D_ * L_;
  const unsigned char* pdb = pad + b * L_;
  const float SCL = 0.125f * 1.44269504089f;  // scale * log2(e); exp via v_exp_f32
  int psw = l15 & 7;

  // staging (512 threads): 1 K-chunk + 1 V-chunk per thread; chunk t -> row t>>3,
  // 16B slot t&7 (source pre-swizzled, LDS dest linear — T2 both-sides rule)
  int srr = t >> 3, ssp = t & 7;
  int sso = (ssp ^ (srr & 7)) << 4;
#define STAGE(bufi, kt0s) do {                                                        \
    gload16((const char*)(Kbh + (size_t)((kt0s) + srr) * D_) + sso, sK[bufi] + t * 16); \
    gload16((const char*)(Vbh + (size_t)srr * L_ + (kt0s)) + sso, sV[bufi] + t * 16);   \
  } while (0)

  int qw0 = qb * 128 + w * 16;
  int bound = qw0 + 15;           // last q-row this wave owns
  // Q fragments: qf[dc] covers d = dc*32 + g*8 .. +7 at q-row qw0 + l15
  const u16* qp = Qb + ((size_t)bh * L_ + qw0 + l15) * D_ + g * 8;
  bf16x8 qf0 = *(const bf16x8*)qp;
  bf16x8 qf1 = *(const bf16x8*)(qp + 32);

  f32x4 zero = {0.f, 0.f, 0.f, 0.f};
  f32x4 oacc[4];
#pragma unroll
  for (int db = 0; db < 4; db++) oacc[db] = zero;
  float mrun = -1e30f, lrun = 0.f;

  STAGE(0, kt_lo << 6);
  int buf = 0;

#pragma unroll 1
  for (int kt = kt_lo; kt < kt_hi; kt++) {
    int kt0 = kt << 6;
    __builtin_amdgcn_sched_barrier(0);
    __builtin_amdgcn_s_barrier();                    // B1: buf^1 free to overwrite
    if (kt + 1 < kt_hi) {
      STAGE(buf ^ 1, (kt + 1) << 6);                 // next tile's loads in flight
      asm volatile("s_waitcnt vmcnt(2)" ::: "memory");  // own tile-kt batch landed
    } else {
      asm volatile("s_waitcnt vmcnt(0)" ::: "memory");  // last tile: full drain
    }
    __builtin_amdgcn_s_barrier();                    // B2: tile kt resident block-wide
    __builtin_amdgcn_sched_barrier(0);

    if (kt0 <= bound) {
      // ---- S^T = mfma(K, Q): lane (g,l15) gets keys kb+4g+r at q-col l15 ----
      float sc[4][4];
#pragma unroll
      for (int s = 0; s < 4; s++) {
        int kb = kt0 + s * 16;
        bool live = (kb <= bound);
        f32x4 st = zero;
        uint32_t pb = 0;
        if (live) {
          int R = s * 16 + l15, sw = l15 & 7;
          bf16x8 kf0 = *(const bf16x8*)(sK[buf] + R * 128 + ((g ^ sw) << 4));
          bf16x8 kf1 = *(const bf16x8*)(sK[buf] + R * 128 + (((4 + g) ^ sw) << 4));
          st = MFMA16(kf0, qf0, st);
          st = MFMA16(kf1, qf1, st);
          pb = *(const uint32_t*)(pdb + kb + 4 * g);
        }
        // wave-uniform fast path: sub-tile fully below diagonal and pad-free
        bool needm = !live || (kb + 15 > qw0) || (__ballot(pb != 0) != 0);
        if (needm) {
#pragma unroll
          for (int r = 0; r < 4; r++) {
            int key = kb + 4 * g + r;
            bool pm = (pb >> (8 * r)) & 0xffu;
            bool msk = !live || pm || (key > qw0 + l15);
            sc[s][r] = msk ? -1e30f : st[r] * SCL;
          }
        } else {
#pragma unroll
          for (int r = 0; r < 4; r++) sc[s][r] = st[r] * SCL;
        }
      }

      // ---- online softmax + P write ----
      float m0 = fmaxf(fmaxf(sc[0][0], sc[0][1]), fmaxf(sc[0][2], sc[0][3]));
      float m1 = fmaxf(fmaxf(sc[1][0], sc[1][1]), fmaxf(sc[1][2], sc[1][3]));
      float m2 = fmaxf(fmaxf(sc[2][0], sc[2][1]), fmaxf(sc[2][2], sc[2][3]));
      float m3 = fmaxf(fmaxf(sc[3][0], sc[3][1]), fmaxf(sc[3][2], sc[3][3]));
      float mt = fmaxf(fmaxf(m0, m1), fmaxf(m2, m3));
      mt = fmaxf(mt, __shfl_xor(mt, 16));
      mt = fmaxf(mt, __shfl_xor(mt, 32));
      float mnew = fmaxf(mrun, mt);
      float al = __builtin_amdgcn_exp2f(mrun - mnew);
      mrun = mnew;
      float rs = 0.f;
      char* pwb = sP[w] + l15 * 128 + (g & 1) * 8;
#pragma unroll
      for (int s = 0; s < 4; s++) {
        float p0 = __builtin_amdgcn_exp2f(sc[s][0] - mnew);
        float p1 = __builtin_amdgcn_exp2f(sc[s][1] - mnew);
        float p2 = __builtin_amdgcn_exp2f(sc[s][2] - mnew);
        float p3 = __builtin_amdgcn_exp2f(sc[s][3] - mnew);
        rs += (p0 + p1) + (p2 + p3);
        uint32_t w0 = cvt_pk_bf16(p0, p1), w1 = cvt_pk_bf16(p2, p3);
        char* dst = pwb + (((2 * s + (g >> 1)) ^ psw) << 4);
        *(uint32_t*)dst = w0;
        *(uint32_t*)(dst + 4) = w1;
      }
      rs += __shfl_xor(rs, 16);
      rs += __shfl_xor(rs, 32);
      lrun = lrun * al + rs;
#pragma unroll
      for (int db = 0; db < 4; db++)
#pragma unroll
        for (int r = 0; r < 4; r++) oacc[db][r] *= al;

      // ---- PV: O^T += V^T . P^T ----
#pragma unroll
      for (int kc = 0; kc < 2; kc++) {
        if (kt0 + 32 * kc <= bound) {
          bf16x8 pf = *(const bf16x8*)(sP[w] + l15 * 128 + (((4 * kc + g) ^ psw) << 4));
#pragma unroll
          for (int db = 0; db < 4; db++) {
            int dR = db * 16 + l15;
            bf16x8 vf = *(const bf16x8*)(sV[buf] + dR * 128 +
                                         (((4 * kc + g) ^ (dR & 7)) << 4));
            oacc[db] = MFMA16(vf, pf, oacc[db]);
          }
        }
      }
    }
    buf ^= 1;
  }

  // epilogue: lane holds O^T[d = db*16 + g*4 + r][q = qw0 + l15], normalized by lrun
  float rl = 1.0f / lrun;
  int q = qw0 + l15;
  if (!split) {
    u16* op = Ob + ((size_t)b * L_ + q) * HD_ + h * D_ + g * 4;
#pragma unroll
    for (int db = 0; db < 4; db++) {
      ushort4 pk;
      pk.x = f2bf(oacc[db][0] * rl);
      pk.y = f2bf(oacc[db][1] * rl);
      pk.z = f2bf(oacc[db][2] * rl);
      pk.w = f2bf(oacc[db][3] * rl);
      *(ushort4*)(op + db * 16) = pk;
    }
  } else {
    size_t prow = (size_t)part * 32768 + (size_t)bh * 1024 + (q - 1024);
    u16* op = Opart + prow * 64 + g * 4;
#pragma unroll
    for (int db = 0; db < 4; db++) {
      ushort4 pk;
      pk.x = f2bf(oacc[db][0] * rl);
      pk.y = f2bf(oacc[db][1] * rl);
      pk.z = f2bf(oacc[db][2] * rl);
      pk.w = f2bf(oacc[db][3] * rl);
      *(ushort4*)(op + db * 16) = pk;
    }
    if (g == 0) {
      mlbuf[prow * 2]     = mrun;   // log2-domain running max
      mlbuf[prow * 2 + 1] = lrun;
    }
  }
#undef STAGE
}

// ---------------- merge of split-KV partials (rows 1024..2047 of each b) --------
// O = (l0*2^(m0-M)*O^0 + l1*2^(m1-M)*O^1) / (l0*2^(m0-M) + l1*2^(m1-M))
__global__ __launch_bounds__(256) void merge_k(
    const u16* __restrict__ Op, const float* __restrict__ ml, u16* __restrict__ Ob)
{
  int tid = blockIdx.x * 256 + threadIdx.x;   // 262144 total
  int d0 = (tid & 7) * 8;
  int row = tid >> 3;                          // bh*1024 + qrel  (32768 rows)
  int qrel = row & 1023, bh = row >> 10;
  int b = bh >> 4, h = bh & 15;
  float m0 = ml[(size_t)row * 2],            l0 = ml[(size_t)row * 2 + 1];
  float m1 = ml[((size_t)32768 + row) * 2],  l1 = ml[((size_t)32768 + row) * 2 + 1];
  float M = fmaxf(m0, m1);
  float w0 = l0 * __builtin_amdgcn_exp2f(m0 - M);
  float w1 = l1 * __builtin_amdgcn_exp2f(m1 - M);
  float rw = 1.0f / (w0 + w1);
  w0 *= rw; w1 *= rw;
  bf16x8 a = *(const bf16x8*)(Op + (size_t)row * 64 + d0);
  bf16x8 c = *(const bf16x8*)(Op + ((size_t)32768 + row) * 64 + d0);
  bf16x8 o;
#pragma unroll
  for (int j = 0; j < 8; j++)
    o[j] = (short)f2bf(w0 * bf2f((u16)a[j]) + w1 * bf2f((u16)c[j]));
  *(bf16x8*)(Ob + ((size_t)b * L_ + 1024 + qrel) * HD_ + h * D_ + d0) = o;
}

extern "C" void kernel_launch(void* const* d_in, const int* in_sizes, int n_in,
                              void* d_out, int out_size, void* d_ws, size_t ws_size,
                              hipStream_t stream) {
  const float* x      = (const float*)d_in[0];
  const float* y      = (const float*)d_in[1];
  const unsigned char* mask = (const unsigned char*)d_in[2];
  const float* Wq_w   = (const float*)d_in[3];
  const float* Wq_b   = (const float*)d_in[4];
  const float* Wkv_w  = (const float*)d_in[5];
  const float* Wkv_b  = (const float*)d_in[6];
  const float* proj_w = (const float*)d_in[7];
  const float* proj_b = (const float*)d_in[8];

  char* ws = (char*)d_ws;
  u16* xb   = (u16*)(ws);                        // 8 MB  (reused as Ob after qkv)
  u16* yb   = (u16*)(ws + (size_t)(8  << 20));   // 8 MB  (reused as Opart after qkv)
  u16* Wqt  = (u16*)(ws + (size_t)(16 << 20));   // 2 MB  (reused as mlbuf after qkv)
  u16* Wkvt = (u16*)(ws + (size_t)(18 << 20));   // 4 MB
  u16* Wpt  = (u16*)(ws + (size_t)(22 << 20));   // 2 MB  (live until proj!)
  u16* Qb   = (u16*)(ws + (size_t)(24 << 20));   // 8 MB
  u16* Kb   = (u16*)(ws + (size_t)(32 << 20));   // 8 MB (V^T follows contiguously)
  u16* Vtb  = (u16*)(ws + (size_t)(40 << 20));   // 8 MB, layout [b,h,d,l]
  u16* Ob   = xb;
  u16* Opart  = yb;                              // dead after qkv; 8 MB exact
  float* mlbuf = (float*)Wqt;                    // dead after qkv; 512 KB of 2 MB

  hipLaunchKernelGGL(cast2_k, dim3(4096), dim3(256), 0, stream, x, y, xb, yb);
  hipLaunchKernelGGL(wtrans_k, dim3(64, 32, 3), dim3(256), 0, stream,
                     Wq_w, Wkv_w, proj_w, Wqt, Wkvt, Wpt);
  // fused: Q = xb@Wq+b -> [b,h,l,d]; KV = yb@Wkv+b -> K [b,h,l,d], V^T [b,h,d,l]
  hipLaunchKernelGGL(qkv_k, dim3(24, 32), dim3(256), 0, stream,
                     xb, yb, Wqt, Wkvt, Wq_b, Wkv_b, Qb, Kb);
  hipLaunchKernelGGL(attn_k, dim3(24, H_, B_), dim3(512), 0, stream,
                     Qb, Kb, Vtb, mask, Ob, Opart, mlbuf);
  hipLaunchKernelGGL(merge_k, dim3(1024), dim3(256), 0, stream, Opart, mlbuf, Ob);
  // out = Ob @ proj + b -> f32
  hipLaunchKernelGGL(gemm_k, dim3(8, 32), dim3(256), 0, stream, Ob, Wpt, proj_b, d_out, 1024);
}

// Round 11
// 133.467 us; speedup vs baseline: 1.1132x; 1.1132x over previous
//
#include <hip/hip_runtime.h>
#include <stdint.h>

#define B_  2
#define L_  2048
#define HD_ 1024
#define H_  16
#define D_  64

typedef unsigned short u16;
typedef __attribute__((ext_vector_type(8))) short bf16x8;
typedef __attribute__((ext_vector_type(4))) float f32x4;

#define MFMA16(a, b, c) __builtin_amdgcn_mfma_f32_16x16x32_bf16((a), (b), (c), 0, 0, 0)

__device__ __forceinline__ void gload16(const void* g, void* l) {
  __builtin_amdgcn_global_load_lds((const __attribute__((address_space(1))) void*)g,
                                   (__attribute__((address_space(3))) void*)l, 16, 0, 0);
}

__device__ __forceinline__ u16 f2bf(float f) {
  union { float f; uint32_t u; } c; c.f = f;
  uint32_t u = c.u + 0x7FFFu + ((c.u >> 16) & 1u);
  return (u16)(u >> 16);
}

__device__ __forceinline__ uint32_t cvt_pk_bf16(float lo, float hi) {
  uint32_t r;
  asm("v_cvt_pk_bf16_f32 %0, %1, %2" : "=v"(r) : "v"(lo), "v"(hi));
  return r;
}

// ---------------- fused cast f32 -> bf16 for x and y (8 elems/thread) ----------------
__global__ void cast2_k(const float* __restrict__ x, const float* __restrict__ y,
                        u16* __restrict__ xb, u16* __restrict__ yb) {
  int bid = blockIdx.x;
  const float* in = bid < 2048 ? x : y;
  u16* out = bid < 2048 ? xb : yb;
  int i = ((bid & 2047) * 256 + threadIdx.x) * 8;   // 2048*256*8 == 4M exact
  float4 a = *(const float4*)(in + i);
  float4 b = *(const float4*)(in + i + 4);
  bf16x8 r;
  r[0] = (short)f2bf(a.x); r[1] = (short)f2bf(a.y); r[2] = (short)f2bf(a.z); r[3] = (short)f2bf(a.w);
  r[4] = (short)f2bf(b.x); r[5] = (short)f2bf(b.y); r[6] = (short)f2bf(b.z); r[7] = (short)f2bf(b.w);
  *(bf16x8*)(out + i) = r;
}

// ---------------- fused transpose+cast of all three weights: dst[n][k]=bf16(src[k][n]) ----
__global__ void wtrans_k(const float* __restrict__ Wq, const float* __restrict__ Wkv,
                         const float* __restrict__ Wp,
                         u16* __restrict__ Wqt, u16* __restrict__ Wkvt, u16* __restrict__ Wpt) {
  int z = blockIdx.z;
  const float* src = z == 0 ? Wq : (z == 1 ? Wkv : Wp);
  u16* dst = z == 0 ? Wqt : (z == 1 ? Wkvt : Wpt);
  int Nfull = (z == 1) ? 2048 : 1024;
  int nb = blockIdx.x * 32;
  if (nb >= Nfull) return;               // block-uniform early out (before any barrier)
  __shared__ float tile[32][33];
  int t = threadIdx.x;
  int tc = t & 31, tr = t >> 5;
  int kb = blockIdx.y * 32;
#pragma unroll
  for (int i = 0; i < 4; i++)
    tile[tr + i * 8][tc] = src[(size_t)(kb + tr + i * 8) * Nfull + nb + tc];
  __syncthreads();
#pragma unroll
  for (int i = 0; i < 4; i++) {
    int nl = tr + i * 8;
    dst[(size_t)(nb + nl) * 1024 + kb + tc] = f2bf(tile[tc][nl]);
  }
}

// ---------------- shared GEMM body (unchanged from R7/R8) ----------------
__device__ __forceinline__ void gemm_body(
    char* sA, char* sB,                 // each 2*16384 bytes (double-buffered)
    const u16* __restrict__ A, const u16* __restrict__ Bt,
    const float* __restrict__ bias, void* __restrict__ outp,
    int N, int epi, int bm, int bn)
{
  int t = threadIdx.x;
  int lane = t & 63, w = t >> 6;
  int g = lane >> 4, l15 = lane & 15;
  int wr = w >> 1, wc = w & 1;

  f32x4 zero = {0.f, 0.f, 0.f, 0.f};
  f32x4 acc[4][4];
#pragma unroll
  for (int mi = 0; mi < 4; mi++)
#pragma unroll
    for (int ni = 0; ni < 4; ni++) acc[mi][ni] = zero;

#define GSTAGE(bufi, k0s) do {                                                          \
    _Pragma("unroll")                                                                   \
    for (int it = 0; it < 4; it++) {                                                    \
      int c = it * 256 + t;             /* 0..1023 16B-chunks per matrix */             \
      int r = c >> 3, sp = c & 7;                                                       \
      int off = (sp ^ (r & 7)) << 4;    /* pre-swizzled global source (T2) */           \
      gload16((const char*)(A + (size_t)(bm + r) * 1024 + (k0s)) + off,                 \
              sA + (bufi) * 16384 + c * 16);                                            \
      gload16((const char*)(Bt + (size_t)(bn + r) * 1024 + (k0s)) + off,                \
              sB + (bufi) * 16384 + c * 16);                                            \
    } } while (0)

  GSTAGE(0, 0);
  int buf = 0;
#pragma unroll 1
  for (int kt = 0; kt < 16; kt++) {
    __builtin_amdgcn_sched_barrier(0);
    __builtin_amdgcn_s_barrier();                      // B1: buf^1 free to overwrite
    if (kt < 15) {
      GSTAGE(buf ^ 1, (kt + 1) << 6);                  // next tile's 8 loads in flight
      asm volatile("s_waitcnt vmcnt(8)" ::: "memory"); // own tile's batch landed
    } else {
      asm volatile("s_waitcnt vmcnt(0)" ::: "memory"); // last tile: full drain
    }
    __builtin_amdgcn_s_barrier();                      // B2: tile kt resident block-wide
    __builtin_amdgcn_sched_barrier(0);

    const char* cA = sA + buf * 16384;
    const char* cB = sB + buf * 16384;
#pragma unroll
    for (int kc = 0; kc < 2; kc++) {
      bf16x8 af[4], bfr[4];
#pragma unroll
      for (int mi = 0; mi < 4; mi++) {
        int r = wr * 64 + mi * 16 + l15;
        af[mi] = *(const bf16x8*)(cA + r * 128 + (((kc * 4 + g) ^ (r & 7)) << 4));
      }
#pragma unroll
      for (int ni = 0; ni < 4; ni++) {
        int r = wc * 64 + ni * 16 + l15;
        bfr[ni] = *(const bf16x8*)(cB + r * 128 + (((kc * 4 + g) ^ (r & 7)) << 4));
      }
#pragma unroll
      for (int mi = 0; mi < 4; mi++)
#pragma unroll
        for (int ni = 0; ni < 4; ni++)
          acc[mi][ni] = MFMA16(af[mi], bfr[ni], acc[mi][ni]);
    }
    buf ^= 1;
  }
#undef GSTAGE

  float bv[4];
#pragma unroll
  for (int ni = 0; ni < 4; ni++) bv[ni] = bias[bn + wc * 64 + ni * 16 + l15];

  if (epi == 2) {
    float* fo = (float*)outp;
#pragma unroll
    for (int mi = 0; mi < 4; mi++)
#pragma unroll
      for (int ni = 0; ni < 4; ni++) {
        int n = bn + wc * 64 + ni * 16 + l15;
#pragma unroll
        for (int r = 0; r < 4; r++) {
          int m = bm + wr * 64 + mi * 16 + g * 4 + r;
          fo[(size_t)m * N + n] = acc[mi][ni][r] + bv[ni];
        }
      }
  } else {
    u16* ob = (u16*)outp;
#pragma unroll
    for (int mi = 0; mi < 4; mi++)
#pragma unroll
      for (int ni = 0; ni < 4; ni++) {
        int n = bn + wc * 64 + ni * 16 + l15;
        int kv = n >> 10;          // 0 for epi0 (N=1024)
        int hh = (n >> 6) & 15;
        int dd = n & 63;
        int m0 = bm + wr * 64 + mi * 16 + g * 4;
        int bb = m0 >> 11, lq0 = m0 & 2047;
        if (epi == 1 && kv == 1) {
          // V stored TRANSPOSED: [b,h,d,l]; r -> lq consecutive -> one 8B store
          ushort4 pk;
          pk.x = f2bf(acc[mi][ni][0] + bv[ni]);
          pk.y = f2bf(acc[mi][ni][1] + bv[ni]);
          pk.z = f2bf(acc[mi][ni][2] + bv[ni]);
          pk.w = f2bf(acc[mi][ni][3] + bv[ni]);
          size_t idx = (size_t)(B_ * H_ * L_ * D_) +
                       (((size_t)(bb * H_ + hh) * D_ + dd) * L_ + lq0);
          *(ushort4*)(ob + idx) = pk;
        } else {
#pragma unroll
          for (int r = 0; r < 4; r++) {
            size_t idx = (((size_t)(bb * H_ + hh) * L_ + lq0 + r) * D_) + dd;
            ob[idx] = f2bf(acc[mi][ni][r] + bv[ni]);
          }
        }
      }
  }
}

// fused Q + KV projection: grid (8+16, 32); bx<8 -> Q-GEMM, else KV-GEMM.
__global__ __launch_bounds__(256) void qkv_k(
    const u16* __restrict__ xb, const u16* __restrict__ yb,
    const u16* __restrict__ Wqt, const u16* __restrict__ Wkvt,
    const float* __restrict__ Wq_b, const float* __restrict__ Wkv_b,
    u16* __restrict__ Qout, u16* __restrict__ KVout)
{
  __shared__ char sA[2 * 16384];
  __shared__ char sB[2 * 16384];
  int bx = blockIdx.x, bm = blockIdx.y * 128;
  if (bx < 8)
    gemm_body(sA, sB, xb, Wqt, Wq_b, (void*)Qout, 1024, 0, bm, bx * 128);
  else
    gemm_body(sA, sB, yb, Wkvt, Wkv_b, (void*)KVout, 2048, 1, bm, (bx - 8) * 128);
}

// proj GEMM (epi2, f32 out)
__global__ __launch_bounds__(256) void gemm_k(
    const u16* __restrict__ A, const u16* __restrict__ Bt,
    const float* __restrict__ bias, void* __restrict__ outp, int N)
{
  __shared__ char sA[2 * 16384];
  __shared__ char sB[2 * 16384];
  gemm_body(sA, sB, A, Bt, bias, outp, N, 2, blockIdx.y * 128, blockIdx.x * 128);
}

// ---------------- flash attention v10 ----------------
// R8 mapping (grid (16,16,2), 512 blocks x 512 threads, complementary pairing)
// + SINGLE-barrier triple-buffered k-loop: stage(kt+1 -> buf[(kt+1)%3]) ->
// vmcnt(2) (own tile-kt loads landed) -> s_barrier (all waves' tile-kt loads
// landed) -> compute(buf[kt%3]). WAR proof: buf[(kt+1)%3] was last read at
// compute(kt-2); every wave staging at iter kt passed barrier(kt-1), which it
// reaches only after its compute(kt-2) in program order -> safe with ONE
// barrier/tile. + T13 defer-rescale at threshold 0 (exactly output-preserving).
__global__ __launch_bounds__(512, 2) void attn_k(
    const u16* __restrict__ Qb, const u16* __restrict__ Kb, const u16* __restrict__ Vt,
    const unsigned char* __restrict__ pad, u16* __restrict__ Ob)
{
  __shared__ char sK[3][8192];   // [buf][key 0..63][128B row], slot s at phys s^(key&7)
  __shared__ char sV[3][8192];   // [buf][d 0..63][128B row = 64 keys], slot s^(d&7)
  __shared__ char sP[8][2048];   // per-wave P^T: [q15][128B = 64 keys], slot s^(q15&7)
  int t = threadIdx.x, lane = t & 63, w = t >> 6, g = lane >> 4, l15 = lane & 15;
  int x = blockIdx.x, h = blockIdx.y, b = blockIdx.z, bh = b * H_ + h;
  int qb = b ? x : 15 - x;        // complementary pairing across the two batch halves

  const u16* Kbh = Kb + (size_t)bh * L_ * D_;
  const u16* Vbh = Vt + (size_t)bh * D_ * L_;
  const unsigned char* pdb = pad + b * L_;
  const float SCL = 0.125f * 1.44269504089f;  // scale * log2(e); exp via v_exp_f32
  int psw = l15 & 7;

  // staging (512 threads): 1 K-chunk + 1 V-chunk per thread; chunk t -> row t>>3,
  // 16B slot t&7 (source pre-swizzled, LDS dest linear — T2 both-sides rule)
  int srr = t >> 3, ssp = t & 7;
  int sso = (ssp ^ (srr & 7)) << 4;
#define STAGE(bufi, kt0s) do {                                                        \
    gload16((const char*)(Kbh + (size_t)((kt0s) + srr) * D_) + sso, sK[bufi] + t * 16); \
    gload16((const char*)(Vbh + (size_t)srr * L_ + (kt0s)) + sso, sV[bufi] + t * 16);   \
  } while (0)

  int qw0 = qb * 128 + w * 16;
  int bound = qw0 + 15;           // last q-row this wave owns
  int nkt = 2 * qb + 2;

  // Q fragments: qf[dc] covers d = dc*32 + g*8 .. +7 at q-row qw0 + l15
  const u16* qp = Qb + ((size_t)bh * L_ + qw0 + l15) * D_ + g * 8;
  bf16x8 qf0 = *(const bf16x8*)qp;
  bf16x8 qf1 = *(const bf16x8*)(qp + 32);

  f32x4 zero = {0.f, 0.f, 0.f, 0.f};
  f32x4 oacc[4];
#pragma unroll
  for (int db = 0; db < 4; db++) oacc[db] = zero;
  float mrun = -1e30f, lrun = 0.f;

  STAGE(0, 0);
  int cb = 0, nb = 1;             // compute buf / next (stage) buf, rotate mod 3

#pragma unroll 1
  for (int kt = 0; kt < nkt; kt++) {
    int kt0 = kt << 6;
    __builtin_amdgcn_sched_barrier(0);
    if (kt + 1 < nkt) {
      STAGE(nb, (kt + 1) << 6);                      // next tile's loads in flight
      asm volatile("s_waitcnt vmcnt(2)" ::: "memory");  // own tile-kt batch landed
    } else {
      asm volatile("s_waitcnt vmcnt(0)" ::: "memory");  // last tile: full drain
    }
    __builtin_amdgcn_s_barrier();                    // all waves' tile-kt loads landed
    __builtin_amdgcn_sched_barrier(0);

    if (kt0 <= bound) {
      // ---- S^T = mfma(K, Q): lane (g,l15) gets keys kb+4g+r at q-col l15 ----
      float sc[4][4];
#pragma unroll
      for (int s = 0; s < 4; s++) {
        int kb = kt0 + s * 16;
        bool live = (kb <= bound);
        f32x4 st = zero;
        uint32_t pb = 0;
        if (live) {
          int R = s * 16 + l15, sw = l15 & 7;
          bf16x8 kf0 = *(const bf16x8*)(sK[cb] + R * 128 + ((g ^ sw) << 4));
          bf16x8 kf1 = *(const bf16x8*)(sK[cb] + R * 128 + (((4 + g) ^ sw) << 4));
          st = MFMA16(kf0, qf0, st);
          st = MFMA16(kf1, qf1, st);
          pb = *(const uint32_t*)(pdb + kb + 4 * g);
        }
        // wave-uniform fast path: sub-tile fully below diagonal and pad-free
        bool needm = !live || (kb + 15 > qw0) || (__ballot(pb != 0) != 0);
        if (needm) {
#pragma unroll
          for (int r = 0; r < 4; r++) {
            int key = kb + 4 * g + r;
            bool pm = (pb >> (8 * r)) & 0xffu;
            bool msk = !live || pm || (key > qw0 + l15);
            sc[s][r] = msk ? -1e30f : st[r] * SCL;
          }
        } else {
#pragma unroll
          for (int r = 0; r < 4; r++) sc[s][r] = st[r] * SCL;
        }
      }

      // ---- online softmax (defer-rescale at threshold 0) + P write ----
      float m0 = fmaxf(fmaxf(sc[0][0], sc[0][1]), fmaxf(sc[0][2], sc[0][3]));
      float m1 = fmaxf(fmaxf(sc[1][0], sc[1][1]), fmaxf(sc[1][2], sc[1][3]));
      float m2 = fmaxf(fmaxf(sc[2][0], sc[2][1]), fmaxf(sc[2][2], sc[2][3]));
      float m3 = fmaxf(fmaxf(sc[3][0], sc[3][1]), fmaxf(sc[3][2], sc[3][3]));
      float mt = fmaxf(fmaxf(m0, m1), fmaxf(m2, m3));
      mt = fmaxf(mt, __shfl_xor(mt, 16));
      mt = fmaxf(mt, __shfl_xor(mt, 32));
      if (!__all(mt <= mrun)) {        // wave-uniform; skip => al==1 exactly
        float mnew = fmaxf(mrun, mt);
        float al = __builtin_amdgcn_exp2f(mrun - mnew);
        mrun = mnew;
        lrun *= al;
#pragma unroll
        for (int db = 0; db < 4; db++)
#pragma unroll
          for (int r = 0; r < 4; r++) oacc[db][r] *= al;
      }
      float rs = 0.f;
      char* pwb = sP[w] + l15 * 128 + (g & 1) * 8;
#pragma unroll
      for (int s = 0; s < 4; s++) {
        float p0 = __builtin_amdgcn_exp2f(sc[s][0] - mrun);
        float p1 = __builtin_amdgcn_exp2f(sc[s][1] - mrun);
        float p2 = __builtin_amdgcn_exp2f(sc[s][2] - mrun);
        float p3 = __builtin_amdgcn_exp2f(sc[s][3] - mrun);
        rs += (p0 + p1) + (p2 + p3);
        uint32_t w0 = cvt_pk_bf16(p0, p1), w1 = cvt_pk_bf16(p2, p3);
        char* dst = pwb + (((2 * s + (g >> 1)) ^ psw) << 4);
        *(uint32_t*)dst = w0;
        *(uint32_t*)(dst + 4) = w1;
      }
      rs += __shfl_xor(rs, 16);
      rs += __shfl_xor(rs, 32);
      lrun += rs;

      // ---- PV: O^T += V^T . P^T ----
#pragma unroll
      for (int kc = 0; kc < 2; kc++) {
        if (kt0 + 32 * kc <= bound) {
          bf16x8 pf = *(const bf16x8*)(sP[w] + l15 * 128 + (((4 * kc + g) ^ psw) << 4));
#pragma unroll
          for (int db = 0; db < 4; db++) {
            int dR = db * 16 + l15;
            bf16x8 vf = *(const bf16x8*)(sV[cb] + dR * 128 +
                                         (((4 * kc + g) ^ (dR & 7)) << 4));
            oacc[db] = MFMA16(vf, pf, oacc[db]);
          }
        }
      }
    }
    cb = (cb == 2) ? 0 : cb + 1;
    nb = (nb == 2) ? 0 : nb + 1;
  }

  // epilogue: lane holds O^T[d = db*16 + g*4 + r][q = qw0 + l15]
  float rl = 1.0f / lrun;
  int q = qw0 + l15;
  u16* op = Ob + ((size_t)b * L_ + q) * HD_ + h * D_ + g * 4;
#pragma unroll
  for (int db = 0; db < 4; db++) {
    ushort4 pk;
    pk.x = f2bf(oacc[db][0] * rl);
    pk.y = f2bf(oacc[db][1] * rl);
    pk.z = f2bf(oacc[db][2] * rl);
    pk.w = f2bf(oacc[db][3] * rl);
    *(ushort4*)(op + db * 16) = pk;
  }
#undef STAGE
}

extern "C" void kernel_launch(void* const* d_in, const int* in_sizes, int n_in,
                              void* d_out, int out_size, void* d_ws, size_t ws_size,
                              hipStream_t stream) {
  const float* x      = (const float*)d_in[0];
  const float* y      = (const float*)d_in[1];
  const unsigned char* mask = (const unsigned char*)d_in[2];
  const float* Wq_w   = (const float*)d_in[3];
  const float* Wq_b   = (const float*)d_in[4];
  const float* Wkv_w  = (const float*)d_in[5];
  const float* Wkv_b  = (const float*)d_in[6];
  const float* proj_w = (const float*)d_in[7];
  const float* proj_b = (const float*)d_in[8];

  char* ws = (char*)d_ws;
  u16* xb   = (u16*)(ws);                        // 8 MB  (reused as Ob after qkv)
  u16* yb   = (u16*)(ws + (size_t)(8  << 20));   // 8 MB
  u16* Wqt  = (u16*)(ws + (size_t)(16 << 20));   // 2 MB
  u16* Wkvt = (u16*)(ws + (size_t)(18 << 20));   // 4 MB
  u16* Wpt  = (u16*)(ws + (size_t)(22 << 20));   // 2 MB
  u16* Qb   = (u16*)(ws + (size_t)(24 << 20));   // 8 MB
  u16* Kb   = (u16*)(ws + (size_t)(32 << 20));   // 8 MB (V^T follows contiguously)
  u16* Vtb  = (u16*)(ws + (size_t)(40 << 20));   // 8 MB, layout [b,h,d,l]
  u16* Ob   = xb;

  hipLaunchKernelGGL(cast2_k, dim3(4096), dim3(256), 0, stream, x, y, xb, yb);
  hipLaunchKernelGGL(wtrans_k, dim3(64, 32, 3), dim3(256), 0, stream,
                     Wq_w, Wkv_w, proj_w, Wqt, Wkvt, Wpt);
  // fused: Q = xb@Wq+b -> [b,h,l,d]; KV = yb@Wkv+b -> K [b,h,l,d], V^T [b,h,d,l]
  hipLaunchKernelGGL(qkv_k, dim3(24, 32), dim3(256), 0, stream,
                     xb, yb, Wqt, Wkvt, Wq_b, Wkv_b, Qb, Kb);
  hipLaunchKernelGGL(attn_k, dim3(16, H_, B_), dim3(512), 0, stream, Qb, Kb, Vtb, mask, Ob);
  // out = Ob @ proj + b -> f32
  hipLaunchKernelGGL(gemm_k, dim3(8, 32), dim3(256), 0, stream, Ob, Wpt, proj_b, d_out, 1024);
}